// Round 1
// baseline (627.263 us; speedup 1.0000x reference)
//
#include <hip/hip_runtime.h>
#include <math.h>

// FusionEncoder: E=1024, F=4096, N=64 docs, L=2 layers, fp32 throughout.
// Pipeline: proj -> [v -> attn -> LN1 -> FFN -> LN2] x2 -> attn-pool -> MLP head.
// All GEMMs are M=64 skinny; weights read exactly once (qkv sliced to v-only).

#define EDIM 1024
#define FDIM 4096

// ---------------- block-wide sum over 256 threads (4 waves) ----------------
__device__ __forceinline__ float block_sum256(float v) {
  __shared__ float lds[4];
  #pragma unroll
  for (int off = 32; off; off >>= 1) v += __shfl_down(v, off);
  const int wid  = threadIdx.x >> 6;
  const int lane = threadIdx.x & 63;
  __syncthreads();                 // protect lds across repeated calls
  if (lane == 0) lds[wid] = v;
  __syncthreads();
  return lds[0] + lds[1] + lds[2] + lds[3];
}

// ---------------- skinny GEMM: C[64][Nout] = A[64][K] @ W[K][Nout] ----------
// block = 256 threads, tile = 64 rows x 64 cols, thread = 4 rows x 4 cols.
// grid.x = Nout/64, grid.y = split-K count (Kt = K/S per block).
// MODE_A: 0 = plain A (lda), 1 = concat(query,doc) virtual A (proj layer).
// SPLIT:  write partials P[s][64][Nout] (no bias); else direct + bias(+relu).
#define FMA4(ACC, S, W4) \
  ACC.x = fmaf(S, W4.x, ACC.x); ACC.y = fmaf(S, W4.y, ACC.y); \
  ACC.z = fmaf(S, W4.z, ACC.z); ACC.w = fmaf(S, W4.w, ACC.w);

template<int MODE_A, int HAS_BIAS, int RELU, int SPLIT>
__global__ __launch_bounds__(256)
void gemm64_k(const float* __restrict__ A, int lda,
              const float* __restrict__ qv, const float* __restrict__ doc,
              const float* __restrict__ W, int ldw,
              const float* __restrict__ bias,
              float* __restrict__ out, int Nout, int Kt)
{
  __shared__ float As[64 * 68];          // stride 68: 16B-aligned rows, ~2-way max conflicts
  const int t  = threadIdx.x;
  const int cg = t & 15;                 // col group -> 4 consecutive cols
  const int rg = t >> 4;                 // row group -> 4 consecutive rows
  const int r0 = rg * 4;
  const int jc = blockIdx.x * 64 + cg * 4;
  const int kb = blockIdx.y * Kt;

  float4 acc[4];
  #pragma unroll
  for (int i = 0; i < 4; ++i) acc[i] = make_float4(0.f, 0.f, 0.f, 0.f);

  for (int k0 = kb; k0 < kb + Kt; k0 += 64) {
    __syncthreads();
    #pragma unroll
    for (int it = 0; it < 16; ++it) {    // stage A[0..63][k0..k0+63]
      int p   = t + it * 256;
      int row = p >> 6, kk = p & 63;
      int k   = k0 + kk;
      float val;
      if (MODE_A == 1) val = (k < EDIM) ? qv[k] : doc[(size_t)row * EDIM + (k - EDIM)];
      else             val = A[(size_t)row * lda + k];
      As[row * 68 + kk] = val;
    }
    __syncthreads();
    const float* wp = W + (size_t)k0 * ldw + jc;
    #pragma unroll 2
    for (int kk4 = 0; kk4 < 64; kk4 += 4) {
      float4 a0 = *(const float4*)(As + (r0 + 0) * 68 + kk4);
      float4 a1 = *(const float4*)(As + (r0 + 1) * 68 + kk4);
      float4 a2 = *(const float4*)(As + (r0 + 2) * 68 + kk4);
      float4 a3 = *(const float4*)(As + (r0 + 3) * 68 + kk4);
      float4 w0 = *(const float4*)(wp + (size_t)(kk4 + 0) * ldw);
      float4 w1 = *(const float4*)(wp + (size_t)(kk4 + 1) * ldw);
      float4 w2 = *(const float4*)(wp + (size_t)(kk4 + 2) * ldw);
      float4 w3 = *(const float4*)(wp + (size_t)(kk4 + 3) * ldw);
      FMA4(acc[0], a0.x, w0) FMA4(acc[0], a0.y, w1) FMA4(acc[0], a0.z, w2) FMA4(acc[0], a0.w, w3)
      FMA4(acc[1], a1.x, w0) FMA4(acc[1], a1.y, w1) FMA4(acc[1], a1.z, w2) FMA4(acc[1], a1.w, w3)
      FMA4(acc[2], a2.x, w0) FMA4(acc[2], a2.y, w1) FMA4(acc[2], a2.z, w2) FMA4(acc[2], a2.w, w3)
      FMA4(acc[3], a3.x, w0) FMA4(acc[3], a3.y, w1) FMA4(acc[3], a3.z, w2) FMA4(acc[3], a3.w, w3)
    }
  }

  float4 b4 = make_float4(0.f, 0.f, 0.f, 0.f);
  if (HAS_BIAS) b4 = *(const float4*)(bias + jc);
  float* o = out + (SPLIT ? (size_t)blockIdx.y * 64 * Nout : 0);
  #pragma unroll
  for (int i = 0; i < 4; ++i) {
    float4 v = acc[i];
    v.x += b4.x; v.y += b4.y; v.z += b4.z; v.w += b4.w;
    if (RELU) { v.x = fmaxf(v.x, 0.f); v.y = fmaxf(v.y, 0.f);
                v.z = fmaxf(v.z, 0.f); v.w = fmaxf(v.w, 0.f); }
    *(float4*)(o + (size_t)(r0 + i) * Nout + jc) = v;
  }
}

// -------- split-K reduce (+bias, +residual, +LayerNorm), Nout=1024 ----------
// grid = 64 blocks (one per row), 256 threads (4 cols each).
template<int LN, int HAS_RES>
__global__ __launch_bounds__(256)
void reduce_row_k(const float* __restrict__ P, int S,
                  const float* __restrict__ bias,
                  const float* __restrict__ res,
                  const float* __restrict__ g, const float* __restrict__ bln,
                  float* __restrict__ out)
{
  const int row = blockIdx.x;
  const int c   = threadIdx.x * 4;
  float4 v = make_float4(0.f, 0.f, 0.f, 0.f);
  for (int s = 0; s < S; ++s) {
    const float4 p = *(const float4*)(P + ((size_t)s * 64 + row) * EDIM + c);
    v.x += p.x; v.y += p.y; v.z += p.z; v.w += p.w;
  }
  const float4 b4 = *(const float4*)(bias + c);
  v.x += b4.x; v.y += b4.y; v.z += b4.z; v.w += b4.w;
  if (HAS_RES) {
    const float4 r4 = *(const float4*)(res + (size_t)row * EDIM + c);
    v.x += r4.x; v.y += r4.y; v.z += r4.z; v.w += r4.w;
  }
  if (LN) {
    float mean = block_sum256(v.x + v.y + v.z + v.w) * (1.f / 1024.f);
    float dx = v.x - mean, dy = v.y - mean, dz = v.z - mean, dw = v.w - mean;
    float var  = block_sum256(dx * dx + dy * dy + dz * dz + dw * dw) * (1.f / 1024.f);
    float inv  = 1.f / sqrtf(var + 1e-5f);
    const float4 g4  = *(const float4*)(g + c);
    const float4 bl4 = *(const float4*)(bln + c);
    v.x = dx * inv * g4.x + bl4.x;
    v.y = dy * inv * g4.y + bl4.y;
    v.z = dz * inv * g4.z + bl4.z;
    v.w = dw * inv * g4.w + bl4.w;
  }
  *(float4*)(out + (size_t)row * EDIM + c) = v;
}

// -------- logits[i] = dot(a[i,:4096], Wa2) + ba2 ; grid = 64 blocks ---------
__global__ __launch_bounds__(256)
void logits_k(const float* __restrict__ a, const float* __restrict__ Wa2,
              const float* __restrict__ ba2, float* __restrict__ logits)
{
  const int i = blockIdx.x;
  const float* ar = a + (size_t)i * FDIM;
  float v = 0.f;
  for (int cidx = threadIdx.x; cidx < FDIM; cidx += 256)
    v = fmaf(ar[cidx], Wa2[cidx], v);
  float s = block_sum256(v);
  if (threadIdx.x == 0) logits[i] = s + ba2[0];
}

// -------- softmax over 64 logits + weighted pool over rows of x -------------
// grid = 4 blocks x 256 threads (covers 1024 cols); block 0 also writes w.
__global__ __launch_bounds__(256)
void pool_k(const float* __restrict__ logits, const float* __restrict__ x,
            float* __restrict__ fused, float* __restrict__ w_out)
{
  __shared__ float l[64];
  __shared__ float wl[64];
  const int t = threadIdx.x;
  if (t < 64) l[t] = logits[t];
  __syncthreads();
  float m = -1e30f;
  for (int i = 0; i < 64; ++i) m = fmaxf(m, l[i]);
  float den = 0.f;
  for (int i = 0; i < 64; ++i) den += expf(l[i] - m);
  if (t < 64) wl[t] = expf(l[t] - m) / den;
  __syncthreads();
  const int j = blockIdx.x * 256 + t;
  float acc = 0.f;
  for (int i = 0; i < 64; ++i) acc = fmaf(wl[i], x[(size_t)i * EDIM + j], acc);
  fused[j] = acc;
  if (blockIdx.x == 0 && t < 64) w_out[t] = wl[t];
}

// -------- GEMV partial: P[s][j] = sum_{k in chunk} vec[k] * W[k][j] ---------
// grid = (Ncol/256, S); KT = K/S staged in LDS; thread = one output col.
template<int KT>
__global__ __launch_bounds__(256)
void gemv_k(const float* __restrict__ vec, const float* __restrict__ W, int Ncol,
            float* __restrict__ P)
{
  __shared__ float vl[KT];
  const int t  = threadIdx.x;
  const int k0 = blockIdx.y * KT;
  for (int k = t; k < KT; k += 256) vl[k] = vec[k0 + k];
  __syncthreads();
  const int j = blockIdx.x * 256 + t;
  const float* wp = W + (size_t)k0 * Ncol + j;
  float acc = 0.f;
  #pragma unroll 8
  for (int kk = 0; kk < KT; ++kk) acc = fmaf(vl[kk], wp[(size_t)kk * Ncol], acc);
  P[(size_t)blockIdx.y * Ncol + j] = acc;
}

template<int RELU>
__global__ __launch_bounds__(256)
void reduce_vec_k(const float* __restrict__ P, int S, int Ncol,
                  const float* __restrict__ bias, float* __restrict__ out)
{
  const int j = blockIdx.x * 256 + threadIdx.x;
  float v = 0.f;
  for (int s = 0; s < S; ++s) v += P[(size_t)s * Ncol + j];
  v += bias[j];
  if (RELU) v = fmaxf(v, 0.f);
  out[j] = v;
}

// ---------------------------------------------------------------------------
extern "C" void kernel_launch(void* const* d_in, const int* in_sizes, int n_in,
                              void* d_out, int out_size, void* d_ws, size_t ws_size,
                              hipStream_t stream) {
  (void)in_sizes; (void)n_in; (void)out_size; (void)ws_size;
  const float* q    = (const float*)d_in[0];
  const float* doc  = (const float*)d_in[1];
  const float* Wp   = (const float*)d_in[2];
  const float* bp   = (const float*)d_in[3];
  const float* Wqkv = (const float*)d_in[4];
  const float* bqkv = (const float*)d_in[5];
  const float* Wo   = (const float*)d_in[6];
  const float* bo   = (const float*)d_in[7];
  const float* ln1g = (const float*)d_in[8];
  const float* ln1b = (const float*)d_in[9];
  const float* ln2g = (const float*)d_in[10];
  const float* ln2b = (const float*)d_in[11];
  const float* W1   = (const float*)d_in[12];
  const float* b1   = (const float*)d_in[13];
  const float* W2   = (const float*)d_in[14];
  const float* b2   = (const float*)d_in[15];
  const float* Wa1  = (const float*)d_in[16];
  const float* ba1  = (const float*)d_in[17];
  const float* Wa2  = (const float*)d_in[18];
  const float* ba2  = (const float*)d_in[19];
  const float* Wf1  = (const float*)d_in[20];
  const float* bf1  = (const float*)d_in[21];
  const float* Wf2  = (const float*)d_in[22];
  const float* bf2  = (const float*)d_in[23];
  float* out = (float*)d_out;
  float* ws  = (float*)d_ws;

  // workspace layout (floats)
  float* x      = ws;                 // 64x1024
  float* v      = ws + 65536;         // 64x1024
  float* h      = ws + 131072;        // 64x4096
  float* a      = ws + 393216;        // 64x4096
  float* P      = ws + 655360;        // up to 8 x 64 x 1024 split-K partials
  float* logits = ws + 1179648;       // 64
  float* fused  = ws + 1179712;       // 1024
  float* Pf     = ws + 1180736;       // 16 x 4096
  float* g      = ws + 1246272;       // 4096
  float* P2     = ws + 1250368;       // 16 x 4096

  const dim3 blk(256);

  // proj: x = concat(q,doc) @ Wp + bp   (K=2048, split 8)
  gemm64_k<1,0,0,1><<<dim3(16,8), blk, 0, stream>>>(nullptr, 0, q, doc, Wp, EDIM, nullptr, P, EDIM, 256);
  reduce_row_k<0,0><<<64, blk, 0, stream>>>(P, 8, bp, nullptr, nullptr, nullptr, x);

  for (int l = 0; l < 2; ++l) {
    const float* Wv = Wqkv + (size_t)l * EDIM * 3 * EDIM + 2 * EDIM;  // v slice only
    gemm64_k<0,0,0,1><<<dim3(16,4), blk, 0, stream>>>(x, EDIM, nullptr, nullptr, Wv, 3 * EDIM, nullptr, P, EDIM, 256);
    reduce_row_k<0,0><<<64, blk, 0, stream>>>(P, 4, bqkv + l * 3 * EDIM + 2 * EDIM, nullptr, nullptr, nullptr, v);

    gemm64_k<0,0,0,1><<<dim3(16,4), blk, 0, stream>>>(v, EDIM, nullptr, nullptr, Wo + (size_t)l * EDIM * EDIM, EDIM, nullptr, P, EDIM, 256);
    reduce_row_k<1,1><<<64, blk, 0, stream>>>(P, 4, bo + l * EDIM, x, ln1g + l * EDIM, ln1b + l * EDIM, x);

    gemm64_k<0,1,1,0><<<dim3(64,1), blk, 0, stream>>>(x, EDIM, nullptr, nullptr, W1 + (size_t)l * EDIM * FDIM, FDIM, b1 + l * FDIM, h, FDIM, EDIM);

    gemm64_k<0,0,0,1><<<dim3(16,8), blk, 0, stream>>>(h, FDIM, nullptr, nullptr, W2 + (size_t)l * FDIM * EDIM, EDIM, nullptr, P, EDIM, 512);
    reduce_row_k<1,1><<<64, blk, 0, stream>>>(P, 8, b2 + l * EDIM, x, ln2g + l * EDIM, ln2b + l * EDIM, x);
  }

  // attention-pool head
  gemm64_k<0,1,1,0><<<dim3(64,1), blk, 0, stream>>>(x, EDIM, nullptr, nullptr, Wa1, FDIM, ba1, a, FDIM, EDIM);
  logits_k<<<64, blk, 0, stream>>>(a, Wa2, ba2, logits);
  pool_k<<<4, blk, 0, stream>>>(logits, x, fused, out + FDIM);

  // final MLP head (GEMVs)
  gemv_k<64><<<dim3(16,16), blk, 0, stream>>>(fused, Wf1, FDIM, Pf);
  reduce_vec_k<1><<<16, blk, 0, stream>>>(Pf, 16, FDIM, bf1, g);
  gemv_k<256><<<dim3(16,16), blk, 0, stream>>>(g, Wf2, FDIM, P2);
  reduce_vec_k<0><<<16, blk, 0, stream>>>(P2, 16, FDIM, bf2, out);
}

// Round 2
// 299.841 us; speedup vs baseline: 2.0920x; 2.0920x over previous
//
#include <hip/hip_runtime.h>
#include <math.h>

// FusionEncoder: E=1024, F=4096, N=64 docs, L=2 layers, fp32 throughout.
// R2: split-K on ALL GEMMs so every dispatch has >=128 blocks (R1 showed the
// grid(64,1) direct GEMMs at 142us, occupancy 2.8% -- latency-bound).

#define EDIM 1024
#define FDIM 4096

// ---------------- block-wide sum over 256 threads (4 waves) ----------------
__device__ __forceinline__ float block_sum256(float v) {
  __shared__ float lds[4];
  #pragma unroll
  for (int off = 32; off; off >>= 1) v += __shfl_down(v, off);
  const int wid  = threadIdx.x >> 6;
  const int lane = threadIdx.x & 63;
  __syncthreads();
  if (lane == 0) lds[wid] = v;
  __syncthreads();
  return lds[0] + lds[1] + lds[2] + lds[3];
}

// ---------------- skinny GEMM: C[64][Nout] = A[64][K] @ W[K][Nout] ----------
// block = 256 threads, tile = 64 rows x 64 cols, thread = 4 rows x 4 cols.
// grid.x = Nout/64, grid.y = split-K index (Kt cols of K per block).
// MODE_A: 0 = plain A (lda), 1 = concat(query,doc) virtual A (proj layer).
// SPLIT:  write partials P[s][64][Nout] (no bias); else direct + bias(+relu).
#define FMA4(ACC, S, W4) \
  ACC.x = fmaf(S, W4.x, ACC.x); ACC.y = fmaf(S, W4.y, ACC.y); \
  ACC.z = fmaf(S, W4.z, ACC.z); ACC.w = fmaf(S, W4.w, ACC.w);

template<int MODE_A, int HAS_BIAS, int RELU, int SPLIT>
__global__ __launch_bounds__(256)
void gemm64_k(const float* __restrict__ A, int lda,
              const float* __restrict__ qv, const float* __restrict__ doc,
              const float* __restrict__ W, int ldw,
              const float* __restrict__ bias,
              float* __restrict__ out, int Nout, int Kt)
{
  __shared__ float As[64 * 68];          // stride 68: 16B-aligned rows, ~2-way max conflicts
  const int t  = threadIdx.x;
  const int cg = t & 15;                 // col group -> 4 consecutive cols
  const int rg = t >> 4;                 // row group -> 4 consecutive rows
  const int r0 = rg * 4;
  const int jc = blockIdx.x * 64 + cg * 4;
  const int kb = blockIdx.y * Kt;

  float4 acc[4];
  #pragma unroll
  for (int i = 0; i < 4; ++i) acc[i] = make_float4(0.f, 0.f, 0.f, 0.f);

  for (int k0 = kb; k0 < kb + Kt; k0 += 64) {
    __syncthreads();
    #pragma unroll
    for (int it = 0; it < 16; ++it) {    // stage A[0..63][k0..k0+63]
      int p   = t + it * 256;
      int row = p >> 6, kk = p & 63;
      int k   = k0 + kk;
      float val;
      if (MODE_A == 1) val = (k < EDIM) ? qv[k] : doc[(size_t)row * EDIM + (k - EDIM)];
      else             val = A[(size_t)row * lda + k];
      As[row * 68 + kk] = val;
    }
    __syncthreads();
    const float* wp = W + (size_t)k0 * ldw + jc;
    #pragma unroll 2
    for (int kk4 = 0; kk4 < 64; kk4 += 4) {
      float4 a0 = *(const float4*)(As + (r0 + 0) * 68 + kk4);
      float4 a1 = *(const float4*)(As + (r0 + 1) * 68 + kk4);
      float4 a2 = *(const float4*)(As + (r0 + 2) * 68 + kk4);
      float4 a3 = *(const float4*)(As + (r0 + 3) * 68 + kk4);
      float4 w0 = *(const float4*)(wp + (size_t)(kk4 + 0) * ldw);
      float4 w1 = *(const float4*)(wp + (size_t)(kk4 + 1) * ldw);
      float4 w2 = *(const float4*)(wp + (size_t)(kk4 + 2) * ldw);
      float4 w3 = *(const float4*)(wp + (size_t)(kk4 + 3) * ldw);
      FMA4(acc[0], a0.x, w0) FMA4(acc[0], a0.y, w1) FMA4(acc[0], a0.z, w2) FMA4(acc[0], a0.w, w3)
      FMA4(acc[1], a1.x, w0) FMA4(acc[1], a1.y, w1) FMA4(acc[1], a1.z, w2) FMA4(acc[1], a1.w, w3)
      FMA4(acc[2], a2.x, w0) FMA4(acc[2], a2.y, w1) FMA4(acc[2], a2.z, w2) FMA4(acc[2], a2.w, w3)
      FMA4(acc[3], a3.x, w0) FMA4(acc[3], a3.y, w1) FMA4(acc[3], a3.z, w2) FMA4(acc[3], a3.w, w3)
    }
  }

  float4 b4 = make_float4(0.f, 0.f, 0.f, 0.f);
  if (HAS_BIAS) b4 = *(const float4*)(bias + jc);
  float* o = out + (SPLIT ? (size_t)blockIdx.y * 64 * Nout : 0);
  #pragma unroll
  for (int i = 0; i < 4; ++i) {
    float4 v = acc[i];
    v.x += b4.x; v.y += b4.y; v.z += b4.z; v.w += b4.w;
    if (RELU) { v.x = fmaxf(v.x, 0.f); v.y = fmaxf(v.y, 0.f);
                v.z = fmaxf(v.z, 0.f); v.w = fmaxf(v.w, 0.f); }
    *(float4*)(o + (size_t)(r0 + i) * Nout + jc) = v;
  }
}

// -------- split-K reduce (+bias, +residual, +LayerNorm), Nout=1024 ----------
// grid = 64 blocks (one per row), 256 threads (4 cols each).
template<int LN, int HAS_RES>
__global__ __launch_bounds__(256)
void reduce_row_k(const float* __restrict__ P, int S,
                  const float* __restrict__ bias,
                  const float* __restrict__ res,
                  const float* __restrict__ g, const float* __restrict__ bln,
                  float* __restrict__ out)
{
  const int row = blockIdx.x;
  const int c   = threadIdx.x * 4;
  float4 v = make_float4(0.f, 0.f, 0.f, 0.f);
  for (int s = 0; s < S; ++s) {
    const float4 p = *(const float4*)(P + ((size_t)s * 64 + row) * EDIM + c);
    v.x += p.x; v.y += p.y; v.z += p.z; v.w += p.w;
  }
  const float4 b4 = *(const float4*)(bias + c);
  v.x += b4.x; v.y += b4.y; v.z += b4.z; v.w += b4.w;
  if (HAS_RES) {
    const float4 r4 = *(const float4*)(res + (size_t)row * EDIM + c);
    v.x += r4.x; v.y += r4.y; v.z += r4.z; v.w += r4.w;
  }
  if (LN) {
    float mean = block_sum256(v.x + v.y + v.z + v.w) * (1.f / 1024.f);
    float dx = v.x - mean, dy = v.y - mean, dz = v.z - mean, dw = v.w - mean;
    float var  = block_sum256(dx * dx + dy * dy + dz * dz + dw * dw) * (1.f / 1024.f);
    float inv  = 1.f / sqrtf(var + 1e-5f);
    const float4 g4  = *(const float4*)(g + c);
    const float4 bl4 = *(const float4*)(bln + c);
    v.x = dx * inv * g4.x + bl4.x;
    v.y = dy * inv * g4.y + bl4.y;
    v.z = dz * inv * g4.z + bl4.z;
    v.w = dw * inv * g4.w + bl4.w;
  }
  *(float4*)(out + (size_t)row * EDIM + c) = v;
}

// -------- wide split-K reduce (+bias+relu) for 64 x FDIM outputs ------------
// grid = 256 blocks x 256 threads, one float4 per thread.
template<int RELU>
__global__ __launch_bounds__(256)
void reduce_wide_k(const float* __restrict__ P, int S,
                   const float* __restrict__ bias, float* __restrict__ out)
{
  const int j4   = blockIdx.x * 256 + threadIdx.x;     // float4 index into 64xFDIM
  const int flat = j4 * 4;
  const int col  = flat & (FDIM - 1);
  float4 v = make_float4(0.f, 0.f, 0.f, 0.f);
  for (int s = 0; s < S; ++s) {
    const float4 p = *(const float4*)(P + (size_t)s * 64 * FDIM + flat);
    v.x += p.x; v.y += p.y; v.z += p.z; v.w += p.w;
  }
  const float4 b4 = *(const float4*)(bias + col);
  v.x += b4.x; v.y += b4.y; v.z += b4.z; v.w += b4.w;
  if (RELU) { v.x = fmaxf(v.x, 0.f); v.y = fmaxf(v.y, 0.f);
              v.z = fmaxf(v.z, 0.f); v.w = fmaxf(v.w, 0.f); }
  *(float4*)(out + flat) = v;
}

// -------- logits[i] = dot(a[i,:4096], Wa2) + ba2 ; grid = 64 blocks ---------
__global__ __launch_bounds__(256)
void logits_k(const float* __restrict__ a, const float* __restrict__ Wa2,
              const float* __restrict__ ba2, float* __restrict__ logits)
{
  const int i = blockIdx.x;
  const float* ar = a + (size_t)i * FDIM;
  float v = 0.f;
  for (int cidx = threadIdx.x; cidx < FDIM; cidx += 256)
    v = fmaf(ar[cidx], Wa2[cidx], v);
  float s = block_sum256(v);
  if (threadIdx.x == 0) logits[i] = s + ba2[0];
}

// -------- softmax over 64 logits + weighted pool over rows of x -------------
__global__ __launch_bounds__(256)
void pool_k(const float* __restrict__ logits, const float* __restrict__ x,
            float* __restrict__ fused, float* __restrict__ w_out)
{
  __shared__ float l[64];
  __shared__ float wl[64];
  const int t = threadIdx.x;
  if (t < 64) l[t] = logits[t];
  __syncthreads();
  float m = -1e30f;
  for (int i = 0; i < 64; ++i) m = fmaxf(m, l[i]);
  float den = 0.f;
  for (int i = 0; i < 64; ++i) den += expf(l[i] - m);
  if (t < 64) wl[t] = expf(l[t] - m) / den;
  __syncthreads();
  const int j = blockIdx.x * 256 + t;
  float acc = 0.f;
  for (int i = 0; i < 64; ++i) acc = fmaf(wl[i], x[(size_t)i * EDIM + j], acc);
  fused[j] = acc;
  if (blockIdx.x == 0 && t < 64) w_out[t] = wl[t];
}

// -------- GEMV partial: P[s][j] = sum_{k in chunk} vec[k] * W[k][j] ---------
template<int KT>
__global__ __launch_bounds__(256)
void gemv_k(const float* __restrict__ vec, const float* __restrict__ W, int Ncol,
            float* __restrict__ P)
{
  __shared__ float vl[KT];
  const int t  = threadIdx.x;
  const int k0 = blockIdx.y * KT;
  for (int k = t; k < KT; k += 256) vl[k] = vec[k0 + k];
  __syncthreads();
  const int j = blockIdx.x * 256 + t;
  const float* wp = W + (size_t)k0 * Ncol + j;
  float acc = 0.f;
  #pragma unroll 8
  for (int kk = 0; kk < KT; ++kk) acc = fmaf(vl[kk], wp[(size_t)kk * Ncol], acc);
  P[(size_t)blockIdx.y * Ncol + j] = acc;
}

template<int RELU>
__global__ __launch_bounds__(256)
void reduce_vec_k(const float* __restrict__ P, int S, int Ncol,
                  const float* __restrict__ bias, float* __restrict__ out)
{
  const int j = blockIdx.x * 256 + threadIdx.x;
  float v = 0.f;
  for (int s = 0; s < S; ++s) v += P[(size_t)s * Ncol + j];
  v += bias[j];
  if (RELU) v = fmaxf(v, 0.f);
  out[j] = v;
}

// ---------------------------------------------------------------------------
extern "C" void kernel_launch(void* const* d_in, const int* in_sizes, int n_in,
                              void* d_out, int out_size, void* d_ws, size_t ws_size,
                              hipStream_t stream) {
  (void)in_sizes; (void)n_in; (void)out_size; (void)ws_size;
  const float* q    = (const float*)d_in[0];
  const float* doc  = (const float*)d_in[1];
  const float* Wp   = (const float*)d_in[2];
  const float* bp   = (const float*)d_in[3];
  const float* Wqkv = (const float*)d_in[4];
  const float* bqkv = (const float*)d_in[5];
  const float* Wo   = (const float*)d_in[6];
  const float* bo   = (const float*)d_in[7];
  const float* ln1g = (const float*)d_in[8];
  const float* ln1b = (const float*)d_in[9];
  const float* ln2g = (const float*)d_in[10];
  const float* ln2b = (const float*)d_in[11];
  const float* W1   = (const float*)d_in[12];
  const float* b1   = (const float*)d_in[13];
  const float* W2   = (const float*)d_in[14];
  const float* b2   = (const float*)d_in[15];
  const float* Wa1  = (const float*)d_in[16];
  const float* ba1  = (const float*)d_in[17];
  const float* Wa2  = (const float*)d_in[18];
  const float* ba2  = (const float*)d_in[19];
  const float* Wf1  = (const float*)d_in[20];
  const float* bf1  = (const float*)d_in[21];
  const float* Wf2  = (const float*)d_in[22];
  const float* bf2  = (const float*)d_in[23];
  float* out = (float*)d_out;
  float* ws  = (float*)d_ws;

  // workspace layout (floats); P (row-partials, <=16x64x1024) and Pw
  // (wide partials, 8x64x4096) share one 2M-float region (sequential use).
  float* x      = ws;                 // 64x1024
  float* v      = ws + 65536;         // 64x1024
  float* h      = ws + 131072;        // 64x4096
  float* a      = ws + 393216;        // 64x4096
  float* P      = ws + 655360;        // 2M floats shared
  float* Pw     = P;
  float* logits = ws + 2752512;       // 64
  float* fused  = ws + 2752576;       // 1024
  float* Pf     = ws + 2753600;       // 16 x 4096
  float* g      = ws + 2819136;       // 4096
  float* P2     = ws + 2823232;       // 64 x 4096

  const dim3 blk(256);

  // proj: x = concat(q,doc) @ Wp + bp   (K=2048, S=16, Kt=128 -> 256 blocks)
  gemm64_k<1,0,0,1><<<dim3(16,16), blk, 0, stream>>>(nullptr, 0, q, doc, Wp, EDIM, nullptr, P, EDIM, 128);
  reduce_row_k<0,0><<<64, blk, 0, stream>>>(P, 16, bp, nullptr, nullptr, nullptr, x);

  for (int l = 0; l < 2; ++l) {
    const float* Wv = Wqkv + (size_t)l * EDIM * 3 * EDIM + 2 * EDIM;  // v slice only
    gemm64_k<0,0,0,1><<<dim3(16,8), blk, 0, stream>>>(x, EDIM, nullptr, nullptr, Wv, 3 * EDIM, nullptr, P, EDIM, 128);
    reduce_row_k<0,0><<<64, blk, 0, stream>>>(P, 8, bqkv + l * 3 * EDIM + 2 * EDIM, nullptr, nullptr, nullptr, v);

    gemm64_k<0,0,0,1><<<dim3(16,8), blk, 0, stream>>>(v, EDIM, nullptr, nullptr, Wo + (size_t)l * EDIM * EDIM, EDIM, nullptr, P, EDIM, 128);
    reduce_row_k<1,1><<<64, blk, 0, stream>>>(P, 8, bo + l * EDIM, x, ln1g + l * EDIM, ln1b + l * EDIM, x);

    // FFN1: K=1024, S=8, Kt=128 -> grid(64,8) = 512 blocks, partials in Pw
    gemm64_k<0,0,0,1><<<dim3(64,8), blk, 0, stream>>>(x, EDIM, nullptr, nullptr, W1 + (size_t)l * EDIM * FDIM, FDIM, nullptr, Pw, FDIM, 128);
    reduce_wide_k<1><<<256, blk, 0, stream>>>(Pw, 8, b1 + l * FDIM, h);

    // FFN2: K=4096, S=16, Kt=256 -> 256 blocks
    gemm64_k<0,0,0,1><<<dim3(16,16), blk, 0, stream>>>(h, FDIM, nullptr, nullptr, W2 + (size_t)l * FDIM * EDIM, EDIM, nullptr, P, EDIM, 256);
    reduce_row_k<1,1><<<64, blk, 0, stream>>>(P, 16, b2 + l * EDIM, x, ln2g + l * EDIM, ln2b + l * EDIM, x);
  }

  // attention-pool head: Wa1 split like FFN1
  gemm64_k<0,0,0,1><<<dim3(64,8), blk, 0, stream>>>(x, EDIM, nullptr, nullptr, Wa1, FDIM, nullptr, Pw, FDIM, 128);
  reduce_wide_k<1><<<256, blk, 0, stream>>>(Pw, 8, ba1, a);
  logits_k<<<64, blk, 0, stream>>>(a, Wa2, ba2, logits);
  pool_k<<<4, blk, 0, stream>>>(logits, x, fused, out + FDIM);

  // final MLP head (GEMVs): Wf1 16MB -> 256 blocks; Wf2 64MB -> 1024 blocks
  gemv_k<64><<<dim3(16,16), blk, 0, stream>>>(fused, Wf1, FDIM, Pf);
  reduce_vec_k<1><<<16, blk, 0, stream>>>(Pf, 16, FDIM, bf1, g);
  gemv_k<64><<<dim3(16,64), blk, 0, stream>>>(g, Wf2, FDIM, P2);
  reduce_vec_k<0><<<16, blk, 0, stream>>>(P2, 64, FDIM, bf2, out);
}

// Round 3
// 230.792 us; speedup vs baseline: 2.7179x; 1.2992x over previous
//
#include <hip/hip_runtime.h>
#include <math.h>

// FusionEncoder: E=1024, F=4096, N=64 docs, L=2 layers, fp32.
// R3: stage BOTH A and W tiles in LDS. R2's gemm loaded W redundantly
// (16 row-groups x same addresses -> 16x VMEM requests per element, kernel
// stuck at 378 GB/s / 9% VALU). Now each W element is fetched once per block.

#define EDIM 1024
#define FDIM 4096

// ---------------- block-wide sum over 256 threads (4 waves) ----------------
__device__ __forceinline__ float block_sum256(float v) {
  __shared__ float lds[4];
  #pragma unroll
  for (int off = 32; off; off >>= 1) v += __shfl_down(v, off);
  const int wid  = threadIdx.x >> 6;
  const int lane = threadIdx.x & 63;
  __syncthreads();
  if (lane == 0) lds[wid] = v;
  __syncthreads();
  return lds[0] + lds[1] + lds[2] + lds[3];
}

// ---------------- skinny GEMM: P[s] = A[64][K_s] @ W[K_s][Nout] -------------
// block = 256 threads, tile = 64 rows x 64 cols, thread = 4 rows x 4 cols.
// A tile AND W tile staged in LDS (stride 68 pad -> <=2-way conflicts, free).
// grid.x = Nout/64, grid.y = split-K index. Always writes partials (no bias).
#define FMA4(ACC, S, W4) \
  ACC.x = fmaf(S, W4.x, ACC.x); ACC.y = fmaf(S, W4.y, ACC.y); \
  ACC.z = fmaf(S, W4.z, ACC.z); ACC.w = fmaf(S, W4.w, ACC.w);

template<int MODE_A>
__global__ __launch_bounds__(256)
void gemm64_k(const float* __restrict__ A, int lda,
              const float* __restrict__ qv, const float* __restrict__ doc,
              const float* __restrict__ W, int ldw,
              float* __restrict__ P, int Nout, int Kt)
{
  __shared__ float As[64 * 68];
  __shared__ float Ws[64 * 68];
  const int t  = threadIdx.x;
  const int cg = t & 15;
  const int rg = t >> 4;
  const int r0 = rg * 4;
  const int jb = blockIdx.x * 64;
  const int jc = jb + cg * 4;
  const int kb = blockIdx.y * Kt;

  float4 acc[4];
  #pragma unroll
  for (int i = 0; i < 4; ++i) acc[i] = make_float4(0.f, 0.f, 0.f, 0.f);

  for (int k0 = kb; k0 < kb + Kt; k0 += 64) {
    __syncthreads();
    // stage A[0..63][k0..k0+63] as float4 (1024 slots / 256 threads)
    #pragma unroll
    for (int it = 0; it < 4; ++it) {
      const int p   = t + it * 256;
      const int row = p >> 4;
      const int c4  = (p & 15) * 4;
      const int k   = k0 + c4;
      float4 val;
      if (MODE_A == 1)
        val = (k < EDIM) ? *(const float4*)(qv + k)
                         : *(const float4*)(doc + (size_t)row * EDIM + (k - EDIM));
      else
        val = *(const float4*)(A + (size_t)row * lda + k);
      *(float4*)(As + row * 68 + c4) = val;
    }
    // stage W[k0..k0+63][jb..jb+63] as float4 — each element fetched ONCE
    #pragma unroll
    for (int it = 0; it < 4; ++it) {
      const int p   = t + it * 256;
      const int row = p >> 4;
      const int c4  = (p & 15) * 4;
      const float4 val = *(const float4*)(W + (size_t)(k0 + row) * ldw + jb + c4);
      *(float4*)(Ws + row * 68 + c4) = val;
    }
    __syncthreads();
    #pragma unroll 4
    for (int kk4 = 0; kk4 < 64; kk4 += 4) {
      const float4 a0 = *(const float4*)(As + (r0 + 0) * 68 + kk4);
      const float4 a1 = *(const float4*)(As + (r0 + 1) * 68 + kk4);
      const float4 a2 = *(const float4*)(As + (r0 + 2) * 68 + kk4);
      const float4 a3 = *(const float4*)(As + (r0 + 3) * 68 + kk4);
      const float4 w0 = *(const float4*)(Ws + (kk4 + 0) * 68 + cg * 4);
      const float4 w1 = *(const float4*)(Ws + (kk4 + 1) * 68 + cg * 4);
      const float4 w2 = *(const float4*)(Ws + (kk4 + 2) * 68 + cg * 4);
      const float4 w3 = *(const float4*)(Ws + (kk4 + 3) * 68 + cg * 4);
      FMA4(acc[0], a0.x, w0) FMA4(acc[0], a0.y, w1) FMA4(acc[0], a0.z, w2) FMA4(acc[0], a0.w, w3)
      FMA4(acc[1], a1.x, w0) FMA4(acc[1], a1.y, w1) FMA4(acc[1], a1.z, w2) FMA4(acc[1], a1.w, w3)
      FMA4(acc[2], a2.x, w0) FMA4(acc[2], a2.y, w1) FMA4(acc[2], a2.z, w2) FMA4(acc[2], a2.w, w3)
      FMA4(acc[3], a3.x, w0) FMA4(acc[3], a3.y, w1) FMA4(acc[3], a3.z, w2) FMA4(acc[3], a3.w, w3)
    }
  }

  float* o = P + (size_t)blockIdx.y * 64 * Nout;
  #pragma unroll
  for (int i = 0; i < 4; ++i)
    *(float4*)(o + (size_t)(r0 + i) * Nout + jc) = acc[i];
}

// -------- split-K reduce (+bias, +residual, +LayerNorm), Nout=1024 ----------
// grid = 64 blocks (one per row), 256 threads (4 cols each).
template<int LN, int HAS_RES>
__global__ __launch_bounds__(256)
void reduce_row_k(const float* __restrict__ P, int S,
                  const float* __restrict__ bias,
                  const float* __restrict__ res,
                  const float* __restrict__ g, const float* __restrict__ bln,
                  float* __restrict__ out)
{
  const int row = blockIdx.x;
  const int c   = threadIdx.x * 4;
  float4 v = make_float4(0.f, 0.f, 0.f, 0.f);
  for (int s = 0; s < S; ++s) {
    const float4 p = *(const float4*)(P + ((size_t)s * 64 + row) * EDIM + c);
    v.x += p.x; v.y += p.y; v.z += p.z; v.w += p.w;
  }
  const float4 b4 = *(const float4*)(bias + c);
  v.x += b4.x; v.y += b4.y; v.z += b4.z; v.w += b4.w;
  if (HAS_RES) {
    const float4 r4 = *(const float4*)(res + (size_t)row * EDIM + c);
    v.x += r4.x; v.y += r4.y; v.z += r4.z; v.w += r4.w;
  }
  if (LN) {
    float mean = block_sum256(v.x + v.y + v.z + v.w) * (1.f / 1024.f);
    float dx = v.x - mean, dy = v.y - mean, dz = v.z - mean, dw = v.w - mean;
    float var  = block_sum256(dx * dx + dy * dy + dz * dz + dw * dw) * (1.f / 1024.f);
    float inv  = 1.f / sqrtf(var + 1e-5f);
    const float4 g4  = *(const float4*)(g + c);
    const float4 bl4 = *(const float4*)(bln + c);
    v.x = dx * inv * g4.x + bl4.x;
    v.y = dy * inv * g4.y + bl4.y;
    v.z = dz * inv * g4.z + bl4.z;
    v.w = dw * inv * g4.w + bl4.w;
  }
  *(float4*)(out + (size_t)row * EDIM + c) = v;
}

// -------- wide split-K reduce (+bias+relu) for 64 x FDIM outputs ------------
template<int RELU>
__global__ __launch_bounds__(256)
void reduce_wide_k(const float* __restrict__ P, int S,
                   const float* __restrict__ bias, float* __restrict__ out)
{
  const int j4   = blockIdx.x * 256 + threadIdx.x;
  const int flat = j4 * 4;
  const int col  = flat & (FDIM - 1);
  float4 v = make_float4(0.f, 0.f, 0.f, 0.f);
  for (int s = 0; s < S; ++s) {
    const float4 p = *(const float4*)(P + (size_t)s * 64 * FDIM + flat);
    v.x += p.x; v.y += p.y; v.z += p.z; v.w += p.w;
  }
  const float4 b4 = *(const float4*)(bias + col);
  v.x += b4.x; v.y += b4.y; v.z += b4.z; v.w += b4.w;
  if (RELU) { v.x = fmaxf(v.x, 0.f); v.y = fmaxf(v.y, 0.f);
              v.z = fmaxf(v.z, 0.f); v.w = fmaxf(v.w, 0.f); }
  *(float4*)(out + flat) = v;
}

// -------- logits[i] = dot(a[i,:4096], Wa2) + ba2 ; grid = 64 blocks ---------
__global__ __launch_bounds__(256)
void logits_k(const float* __restrict__ a, const float* __restrict__ Wa2,
              const float* __restrict__ ba2, float* __restrict__ logits)
{
  const int i = blockIdx.x;
  const float* ar = a + (size_t)i * FDIM;
  float v = 0.f;
  for (int cidx = threadIdx.x; cidx < FDIM; cidx += 256)
    v = fmaf(ar[cidx], Wa2[cidx], v);
  float s = block_sum256(v);
  if (threadIdx.x == 0) logits[i] = s + ba2[0];
}

// -------- softmax over 64 logits + weighted pool over rows of x -------------
__global__ __launch_bounds__(256)
void pool_k(const float* __restrict__ logits, const float* __restrict__ x,
            float* __restrict__ fused, float* __restrict__ w_out)
{
  __shared__ float l[64];
  __shared__ float wl[64];
  const int t = threadIdx.x;
  if (t < 64) l[t] = logits[t];
  __syncthreads();
  float m = -1e30f;
  for (int i = 0; i < 64; ++i) m = fmaxf(m, l[i]);
  float den = 0.f;
  for (int i = 0; i < 64; ++i) den += expf(l[i] - m);
  if (t < 64) wl[t] = expf(l[t] - m) / den;
  __syncthreads();
  const int j = blockIdx.x * 256 + t;
  float acc = 0.f;
  for (int i = 0; i < 64; ++i) acc = fmaf(wl[i], x[(size_t)i * EDIM + j], acc);
  fused[j] = acc;
  if (blockIdx.x == 0 && t < 64) w_out[t] = wl[t];
}

// -------- GEMV partial (float4/lane): P[s][j..j+3] ---------------------------
// block covers 1024 cols; grid.x = Ncol/1024, grid.y = split-K count.
template<int KT>
__global__ __launch_bounds__(256)
void gemv_k(const float* __restrict__ vec, const float* __restrict__ W, int Ncol,
            float* __restrict__ P)
{
  __shared__ float vl[KT];
  const int t  = threadIdx.x;
  const int k0 = blockIdx.y * KT;
  for (int k = t; k < KT; k += 256) vl[k] = vec[k0 + k];
  __syncthreads();
  const int j = blockIdx.x * 1024 + t * 4;
  const float* wp = W + (size_t)k0 * Ncol + j;
  float4 acc = make_float4(0.f, 0.f, 0.f, 0.f);
  #pragma unroll 8
  for (int kk = 0; kk < KT; ++kk) {
    const float4 w = *(const float4*)(wp + (size_t)kk * Ncol);
    const float s = vl[kk];
    acc.x = fmaf(s, w.x, acc.x); acc.y = fmaf(s, w.y, acc.y);
    acc.z = fmaf(s, w.z, acc.z); acc.w = fmaf(s, w.w, acc.w);
  }
  *(float4*)(P + (size_t)blockIdx.y * Ncol + j) = acc;
}

template<int RELU>
__global__ __launch_bounds__(256)
void reduce_vec_k(const float* __restrict__ P, int S, int Ncol,
                  const float* __restrict__ bias, float* __restrict__ out)
{
  const int j = blockIdx.x * 256 + threadIdx.x;
  float v = 0.f;
  for (int s = 0; s < S; ++s) v += P[(size_t)s * Ncol + j];
  v += bias[j];
  if (RELU) v = fmaxf(v, 0.f);
  out[j] = v;
}

// ---------------------------------------------------------------------------
extern "C" void kernel_launch(void* const* d_in, const int* in_sizes, int n_in,
                              void* d_out, int out_size, void* d_ws, size_t ws_size,
                              hipStream_t stream) {
  (void)in_sizes; (void)n_in; (void)out_size; (void)ws_size;
  const float* q    = (const float*)d_in[0];
  const float* doc  = (const float*)d_in[1];
  const float* Wp   = (const float*)d_in[2];
  const float* bp   = (const float*)d_in[3];
  const float* Wqkv = (const float*)d_in[4];
  const float* bqkv = (const float*)d_in[5];
  const float* Wo   = (const float*)d_in[6];
  const float* bo   = (const float*)d_in[7];
  const float* ln1g = (const float*)d_in[8];
  const float* ln1b = (const float*)d_in[9];
  const float* ln2g = (const float*)d_in[10];
  const float* ln2b = (const float*)d_in[11];
  const float* W1   = (const float*)d_in[12];
  const float* b1   = (const float*)d_in[13];
  const float* W2   = (const float*)d_in[14];
  const float* b2   = (const float*)d_in[15];
  const float* Wa1  = (const float*)d_in[16];
  const float* ba1  = (const float*)d_in[17];
  const float* Wa2  = (const float*)d_in[18];
  const float* ba2  = (const float*)d_in[19];
  const float* Wf1  = (const float*)d_in[20];
  const float* bf1  = (const float*)d_in[21];
  const float* Wf2  = (const float*)d_in[22];
  const float* bf2  = (const float*)d_in[23];
  float* out = (float*)d_out;
  float* ws  = (float*)d_ws;

  // workspace layout (floats); P region (2M floats) is reused sequentially:
  // gemm partials -> (after pool) GEMV partials Pf/P2.
  float* x      = ws;                 // 64x1024
  float* v      = ws + 65536;         // 64x1024
  float* h      = ws + 131072;        // 64x4096
  float* a      = ws + 393216;        // 64x4096
  float* P      = ws + 655360;        // 2M floats shared
  float* Pw     = P;
  float* logits = ws + 2752512;       // 64
  float* fused  = ws + 2752576;       // 1024
  float* g      = ws + 2753600;       // 4096
  float* Pf     = P;                  // 64 x 4096 (P region is dead by then)
  float* P2     = P + 262144;         // 64 x 4096

  const dim3 blk(256);

  // proj: x = concat(q,doc) @ Wp + bp   (K=2048, S=16, Kt=128 -> 256 blocks)
  gemm64_k<1><<<dim3(16,16), blk, 0, stream>>>(nullptr, 0, q, doc, Wp, EDIM, P, EDIM, 128);
  reduce_row_k<0,0><<<64, blk, 0, stream>>>(P, 16, bp, nullptr, nullptr, nullptr, x);

  for (int l = 0; l < 2; ++l) {
    const float* Wv = Wqkv + (size_t)l * EDIM * 3 * EDIM + 2 * EDIM;  // v slice only
    gemm64_k<0><<<dim3(16,16), blk, 0, stream>>>(x, EDIM, nullptr, nullptr, Wv, 3 * EDIM, P, EDIM, 64);
    reduce_row_k<0,0><<<64, blk, 0, stream>>>(P, 16, bqkv + l * 3 * EDIM + 2 * EDIM, nullptr, nullptr, nullptr, v);

    gemm64_k<0><<<dim3(16,16), blk, 0, stream>>>(v, EDIM, nullptr, nullptr, Wo + (size_t)l * EDIM * EDIM, EDIM, P, EDIM, 64);
    reduce_row_k<1,1><<<64, blk, 0, stream>>>(P, 16, bo + l * EDIM, x, ln1g + l * EDIM, ln1b + l * EDIM, x);

    // FFN1: K=1024, S=8 -> grid(64,8) = 512 blocks
    gemm64_k<0><<<dim3(64,8), blk, 0, stream>>>(x, EDIM, nullptr, nullptr, W1 + (size_t)l * EDIM * FDIM, FDIM, Pw, FDIM, 128);
    reduce_wide_k<1><<<256, blk, 0, stream>>>(Pw, 8, b1 + l * FDIM, h);

    // FFN2: K=4096, S=32 -> grid(16,32) = 512 blocks
    gemm64_k<0><<<dim3(16,32), blk, 0, stream>>>(h, FDIM, nullptr, nullptr, W2 + (size_t)l * FDIM * EDIM, EDIM, P, EDIM, 128);
    reduce_row_k<1,1><<<64, blk, 0, stream>>>(P, 32, b2 + l * EDIM, x, ln2g + l * EDIM, ln2b + l * EDIM, x);
  }

  // attention-pool head
  gemm64_k<0><<<dim3(64,8), blk, 0, stream>>>(x, EDIM, nullptr, nullptr, Wa1, FDIM, Pw, FDIM, 128);
  reduce_wide_k<1><<<256, blk, 0, stream>>>(Pw, 8, ba1, a);
  logits_k<<<64, blk, 0, stream>>>(a, Wa2, ba2, logits);
  pool_k<<<4, blk, 0, stream>>>(logits, x, fused, out + FDIM);

  // final MLP head (GEMVs): Wf1 16MB, Wf2 64MB; 256 blocks each, float4/lane
  gemv_k<16><<<dim3(4,64), blk, 0, stream>>>(fused, Wf1, FDIM, Pf);
  reduce_vec_k<1><<<16, blk, 0, stream>>>(Pf, 64, FDIM, bf1, g);
  gemv_k<64><<<dim3(4,64), blk, 0, stream>>>(g, Wf2, FDIM, P2);
  reduce_vec_k<0><<<16, blk, 0, stream>>>(P2, 64, FDIM, bf2, out);
}